// Round 13
// baseline (117.867 us; speedup 1.0000x reference)
//
#include <hip/hip_runtime.h>
#include <stdint.h>

// ---------------------------------------------------------------------------
// CommNetActor fused forward v13 — FP16 MFMA, fat blocks + preload chain.
//
//  R12 post-mortem: 94us rocprof, no pipe >27% — latency-bound on the
//  7-barrier serial path x16 blocks/CU and per-layer L2 B-load stalls.
//  v13 (arithmetic BIT-IDENTICAL to v12; absmax must stay 4.882812e-4):
//   1. 128-row blocks, 512 thr (8 waves: wr in {0,1} x wc in {0..3}):
//      2048 blocks -> 8 sequential blocks/CU (was 16); weight L2 traffic
//      halves to 426MB. fp16 footprint (~64 VGPR) fits (512,4)=128.
//   2. Cross-barrier B-preload chain: each layer's epilogue hoist-loads the
//      NEXT layer's B-frags; they stay in vmcnt flight across the lgkm-only
//      barrier. SEG_W2 = SEG_W1 + 8*2048 (contiguous) -> fc3 hoists 12
//      chunks (W1[8] + W2[0..3]); W2 ring-4 inside cl4 bands; dec hoisted
//      during cl4. No K-loop ever waits on a fresh L2 load.
//  Unchanged: operand-swapped MFMA (lane = X-row, reg-quads = col quads),
//  xswz LDS layout, fused comm via shfl_xor, atomic dec reduce, lgkm-only
//  barriers. MFMA C/D: col=lane&31, row=(r&3)+8*(r>>2)+4*(lane>>5).
//  LDS 66.1KB -> 2 blocks/CU = 16 waves/CU.
// ---------------------------------------------------------------------------

typedef __attribute__((ext_vector_type(4)))  float f32x4;
typedef __attribute__((ext_vector_type(16))) float f32x16;
typedef __attribute__((ext_vector_type(8)))  _Float16 f16x8;
typedef __attribute__((ext_vector_type(4)))  _Float16 f16x4;

#define WS_HALF 106496   // total f16 elements in ws
#define SEG_ENC 0
#define SEG_FC1 8192
#define SEG_FC2 24576
#define SEG_FC3 40960
#define SEG_W1  57344
#define SEG_W2  73728    // = SEG_W1 + 8*2048 (contiguous after W1)
#define SEG_DEC 90112

#define MFMA16(a, b, c) __builtin_amdgcn_mfma_f32_32x32x16_f16((a), (b), (c), 0, 0, 0)

__device__ __forceinline__ unsigned short f16_bits(float f) {
  union { _Float16 h; unsigned short u; } cv;
  cv.h = (_Float16)f;   // RN-E
  return cv.u;
}
__device__ __forceinline__ f32x16 zero16() {
  f32x16 v;
#pragma unroll
  for (int i = 0; i < 16; ++i) v[i] = 0.0f;
  return v;
}
// swizzled f16 index: pitch 128, 16B groups XOR'd by row&15
__device__ __forceinline__ int xswz(int row, int g) {
  return row * 128 + ((g ^ (row & 15)) << 3);
}
// barrier draining LDS ops only — register-bound global loads stay in flight
__device__ __forceinline__ void barrier_lds() {
  asm volatile("s_waitcnt lgkmcnt(0)\n\ts_barrier" ::: "memory");
}

// ---------------------------------------------------------------------------
// Weight prep: f16 fragments. Frag f = kc*nbN + nb:
//   value = W[kc*16 + (lane>>5)*8 + j][nb*32 + (lane&31)]
// cl4 split into W1 = Wtop - 0.25*Wbot and W2 = 0.25*Wbot. dec padded N16->32.
// ---------------------------------------------------------------------------
__global__ void prep_weights(const float* __restrict__ enc_w, const float* __restrict__ fc1_w,
                             const float* __restrict__ fc2_w, const float* __restrict__ fc3_w,
                             const float* __restrict__ cl4_w, const float* __restrict__ dec_w,
                             unsigned short* __restrict__ ws) {
  int idx = blockIdx.x * 256 + threadIdx.x;
  if (idx >= WS_HALF) return;
  const float* W; int base, N, nbN, mode;
  if      (idx <  8192) { W = enc_w; base = SEG_ENC; N = 128; nbN = 4; mode = 0; }
  else if (idx < 24576) { W = fc1_w; base = SEG_FC1; N = 128; nbN = 4; mode = 0; }
  else if (idx < 40960) { W = fc2_w; base = SEG_FC2; N = 128; nbN = 4; mode = 0; }
  else if (idx < 57344) { W = fc3_w; base = SEG_FC3; N = 128; nbN = 4; mode = 0; }
  else if (idx < 73728) { W = cl4_w; base = SEG_W1;  N = 128; nbN = 4; mode = 1; }
  else if (idx < 90112) { W = cl4_w; base = SEG_W2;  N = 128; nbN = 4; mode = 2; }
  else                  { W = dec_w; base = SEG_DEC; N = 16;  nbN = 1; mode = 0; }
  int local = idx - base;
  int j    = local & 7;
  int lane = (local >> 3) & 63;
  int frag = local >> 9;
  int nb = frag % nbN;
  int kc = frag / nbN;
  int k = kc * 16 + ((lane >> 5) << 3) + j;
  int n = nb * 32 + (lane & 31);
  float wv;
  if (mode == 0)      wv = (n < N) ? W[k * N + n] : 0.0f;
  else if (mode == 1) wv = W[k * 128 + n] - 0.25f * W[(k + 128) * 128 + n];
  else                wv = 0.25f * W[(k + 128) * 128 + n];
  ws[idx] = f16_bits(wv);
}

// ---------------------------------------------------------------------------
// Standard layer: Xsrc[128][K] @ W[K][128] + b, act -> Xdst (ping-pong).
// Wave (wr,wc): rows wr*64..+63 (acc0/acc1), cols wc*32..+31. B-fragments
// come preloaded in Bc; after the epilogue, KCN chunks of the NEXT segment
// are hoist-loaded into Bn (they fly across the following lgkm-only barrier).
// ---------------------------------------------------------------------------
template <int KC, int ACT, int KCN>
__device__ __forceinline__ void layer_std(const short* __restrict__ Xsrc,
                                          short* __restrict__ Xdst,
                                          const f16x8 (&Bc)[16],
                                          const unsigned short* nxt,
                                          f16x8 (&Bn)[16],
                                          const float* __restrict__ bias,
                                          int lr, int lh, int wr, int wc) {
  f32x4 bv[4];
#pragma unroll
  for (int q = 0; q < 4; ++q)
    bv[q] = *(const f32x4*)&bias[wc * 32 + q * 8 + 4 * lh];
  f32x16 acc0 = zero16(), acc1 = zero16();
#pragma unroll
  for (int kc = 0; kc < KC; ++kc) {
    const int g = kc * 2 + lh;
    const int xi0 = xswz(wr * 64 + lr, g);
    const int xi1 = xswz(wr * 64 + 32 + lr, g);
    const f16x8 ah0 = *(const f16x8*)&Xsrc[xi0];
    const f16x8 ah1 = *(const f16x8*)&Xsrc[xi1];
    acc0 = MFMA16(Bc[kc], ah0, acc0);
    acc1 = MFMA16(Bc[kc], ah1, acc1);
  }
  // epilogue (frees acc) ...
#pragma unroll
  for (int mb = 0; mb < 2; ++mb) {
    const int row = wr * 64 + mb * 32 + lr;
    const int rb = row & 15;
    const f32x16 a = mb ? acc1 : acc0;
#pragma unroll
    for (int q = 0; q < 4; ++q) {
      f16x4 hq;
#pragma unroll
      for (int t = 0; t < 4; ++t) {
        float v = a[q * 4 + t] + bv[q][t];
        if (ACT == 0)      v = __builtin_amdgcn_rcpf(1.0f + __expf(-v));  // sigmoid
        else if (ACT == 1) v = fmaxf(v, 0.0f);                            // relu
        hq[t] = (_Float16)v;
      }
      const int idx = row * 128 + (((wc * 4 + q) ^ rb) << 3) + 4 * lh;
      *(f16x4*)&Xdst[idx] = hq;
    }
  }
  // ... then hoist next-layer B (rides vmcnt across the barrier)
#pragma unroll
  for (int k = 0; k < KCN; ++k)
    Bn[k] = *(const f16x8*)(nxt + k * 2048);
}

// ---------------------------------------------------------------------------
// cl4 band MB (rows wr*64+MB*32..+31, cols wc*32..+31): a1=(H3@W1)^T,
// a2=(H3@W2)^T. W1 = B[0..7] (fully resident, shared by both bands);
// W2 ring-4 in B[8..11], refilled for the next band after the loop.
// Agents = adjacent lanes -> T = shfl_xor(1)+shfl_xor(2). Writes Xdst.
// ---------------------------------------------------------------------------
template <int MB>
__device__ __forceinline__ void cl4_band(const short* __restrict__ Xsrc,
                                         short* __restrict__ Xdst,
                                         f16x8 (&B)[16],
                                         const unsigned short* b2p,
                                         const float* __restrict__ cl4_b,
                                         int lr, int lh, int wr, int wc) {
  f32x4 bv[4];
#pragma unroll
  for (int q = 0; q < 4; ++q)
    bv[q] = *(const f32x4*)&cl4_b[wc * 32 + q * 8 + 4 * lh];
  f32x16 a1 = zero16(), a2 = zero16();
#pragma unroll
  for (int kc = 0; kc < 8; ++kc) {
    const int xi = xswz(wr * 64 + MB * 32 + lr, kc * 2 + lh);
    const f16x8 ah = *(const f16x8*)&Xsrc[xi];
    a1 = MFMA16(B[kc], ah, a1);
    a2 = MFMA16(B[8 + (kc & 3)], ah, a2);
    if (kc < 4) B[8 + kc] = *(const f16x8*)(b2p + (kc + 4) * 2048);
  }
  // refill W2[0..3] for the next band (harmless L2-hot reload on band 1)
#pragma unroll
  for (int j = 0; j < 4; ++j)
    B[8 + j] = *(const f16x8*)(b2p + j * 2048);
  const int row = wr * 64 + MB * 32 + lr;
  const int rb = row & 15;
#pragma unroll
  for (int q = 0; q < 4; ++q) {
    f16x4 hq;
#pragma unroll
    for (int t = 0; t < 4; ++t) {
      const int r = q * 4 + t;
      float t2 = a2[r];
      t2 += __shfl_xor(t2, 1);   // agents are adjacent lanes 4b..4b+3
      t2 += __shfl_xor(t2, 2);
      hq[t] = (_Float16)(a1[r] + t2 + bv[q][t]);
    }
    const int idx = row * 128 + (((wc * 4 + q) ^ rb) << 3) + 4 * lh;
    *(f16x4*)&Xdst[idx] = hq;
  }
}

// ---------------------------------------------------------------------------
__global__ __launch_bounds__(512, 4)
void commnet_fwd(const float* __restrict__ O,
                 const float* __restrict__ enc_b, const float* __restrict__ fc1_b,
                 const float* __restrict__ fc2_b, const float* __restrict__ fc3_b,
                 const float* __restrict__ cl4_b, const float* __restrict__ dec_b,
                 const unsigned short* __restrict__ ws, float* __restrict__ out) {
  __shared__ __attribute__((aligned(16))) short X0[128 * 128];  // 32 KB
  __shared__ __attribute__((aligned(16))) short X1[128 * 128];  // 32 KB
  __shared__ __attribute__((aligned(16))) float Pbuf[544];      // 2.1 KB (32x17)

  const int tid = threadIdx.x;
  const int l = tid & 63, w = tid >> 6;        // w in 0..7
  const int lr = l & 31, lh = l >> 5;
  const int wr = w >> 2, wc = w & 3;

  // zero ALL 544 partial slots (R9 lesson)
  Pbuf[tid] = 0.0f;
  if (tid < 32) Pbuf[512 + tid] = 0.0f;

  f16x8 BA[16], BB[16];

  // preload enc B (4 chunks) before staging — in flight during the O loads
  {
    const unsigned short* p = ws + SEG_ENC + wc * 512 + l * 8;
#pragma unroll
    for (int k = 0; k < 4; ++k) BA[k] = *(const f16x8*)(p + k * 2048);
  }

  // ---- stage O [128 x 64] f32 -> f16 -> swizzled X0 groups 0..7 ----
  {
    const f32x4* Og = (const f32x4*)(O + (long)blockIdx.x * 8192);
#pragma unroll
    for (int it = 0; it < 4; ++it) {
      const int i = it * 512 + tid;       // 0..2047
      const int row = i >> 4;             // 0..127
      const int c4 = (i & 15) << 2;
      f32x4 v = Og[i];
      f16x4 hv;
#pragma unroll
      for (int j = 0; j < 4; ++j) hv[j] = (_Float16)v[j];
      const int bi = row * 128 + (((c4 >> 3) ^ (row & 15)) << 3) + (c4 & 7);
      *(f16x4*)&X0[bi] = hv;
    }
  }
  barrier_lds();   // X0 staged

  const int base = wc * 512 + l * 8;
  layer_std<4, 0, 8>(X0, X1, BA, ws + SEG_FC1 + base, BB, enc_b, lr, lh, wr, wc);
  barrier_lds();   // H0 in X1
  layer_std<8, 1, 8>(X1, X0, BB, ws + SEG_FC2 + base, BA, fc1_b, lr, lh, wr, wc);
  barrier_lds();   // H1 in X0
  layer_std<8, 1, 8>(X0, X1, BA, ws + SEG_FC3 + base, BB, fc2_b, lr, lh, wr, wc);
  barrier_lds();   // H2 in X1
  // fc3 hoists 12 chunks: W1[0..7] + W2[0..3] (SEG_W2 contiguous after SEG_W1)
  layer_std<8, 1, 12>(X1, X0, BB, ws + SEG_W1 + base, BA, fc3_b, lr, lh, wr, wc);
  barrier_lds();   // H3 in X0

  // ---- cl4: both bands read X0, write X1; W1 resident, W2 ring ----
  const unsigned short* b2p = ws + SEG_W2 + base;
  cl4_band<0>(X0, X1, BA, b2p, cl4_b, lr, lh, wr, wc);
  cl4_band<1>(X0, X1, BA, b2p, cl4_b, lr, lh, wr, wc);
  // hoist dec B (4 chunks per wave, stride 512) across the barrier
  {
    const unsigned short* dp = ws + SEG_DEC + (w * 4) * 512 + l * 8;
#pragma unroll
    for (int k = 0; k < 4; ++k) BB[k] = *(const f16x8*)(dp + k * 512);
  }
  barrier_lds();   // H4 in X1

  // ---- dec: [32 x 512] @ dec_w(pad32); 4 kc per wave; LDS atomic reduce ----
  {
    f32x16 dacc = zero16();
#pragma unroll
    for (int kq = 0; kq < 4; ++kq) {
      const int kcg = w * 4 + kq;          // global k-chunk 0..31
      const int k0 = kcg * 16 + lh * 8;    // 0..504
      const int agent = k0 >> 7;
      const int d0 = k0 & 127;
      const int row = lr * 4 + agent;      // batch lr (0..31), agent
      const int xi = xswz(row, d0 >> 3);
      const f16x8 ah = *(const f16x8*)&X1[xi];
      dacc = MFMA16(BB[kq], ah, dacc);     // swapped: weights in A-slot
    }
    // lane = batch (0..31); reg r (r<8) -> action (r&3)+8*(r>>2)+4*lh
#pragma unroll
    for (int r = 0; r < 8; ++r) {
      const int action = (r & 3) + 8 * (r >> 2) + 4 * lh;   // 0..15
      atomicAdd(&Pbuf[lr * 17 + action], dacc[r]);
    }
  }
  barrier_lds();   // partials complete

  // ---- + bias, softmax over 16 actions, coalesced store ----
  {
    const int c = tid & 15;
    float v = Pbuf[(tid >> 4) * 17 + c] + dec_b[c];
    float m = v;
#pragma unroll
    for (int mk = 1; mk < 16; mk <<= 1) m = fmaxf(m, __shfl_xor(m, mk, 16));
    const float e = __expf(v - m);
    float s = e;
#pragma unroll
    for (int mk = 1; mk < 16; mk <<= 1) s += __shfl_xor(s, mk, 16);
    out[(long)blockIdx.x * 512 + tid] = e * __builtin_amdgcn_rcpf(s);
  }
}

// ---------------------------------------------------------------------------
extern "C" void kernel_launch(void* const* d_in, const int* in_sizes, int n_in,
                              void* d_out, int out_size, void* d_ws, size_t ws_size,
                              hipStream_t stream) {
  (void)n_in; (void)out_size; (void)ws_size;  // needs ws_size >= 212,992 B
  const float* O     = (const float*)d_in[0];
  const float* enc_w = (const float*)d_in[1];
  const float* enc_b = (const float*)d_in[2];
  const float* fc1_w = (const float*)d_in[3];
  const float* fc1_b = (const float*)d_in[4];
  const float* fc2_w = (const float*)d_in[5];
  const float* fc2_b = (const float*)d_in[6];
  const float* fc3_w = (const float*)d_in[7];
  const float* fc3_b = (const float*)d_in[8];
  const float* cl4_w = (const float*)d_in[9];
  const float* cl4_b = (const float*)d_in[10];
  const float* dec_w = (const float*)d_in[11];
  const float* dec_b = (const float*)d_in[12];
  unsigned short* wsb = (unsigned short*)d_ws;

  prep_weights<<<(WS_HALF + 255) / 256, 256, 0, stream>>>(enc_w, fc1_w, fc2_w, fc3_w,
                                                          cl4_w, dec_w, wsb);
  const int rows   = in_sizes[0] / 64;   // B*A = 262144
  const int blocks = rows / 128;         // 2048
  commnet_fwd<<<blocks, 512, 0, stream>>>(O, enc_b, fc1_b, fc2_b, fc3_b, cl4_b,
                                          dec_b, wsb, (float*)d_out);
}

// Round 14
// 115.043 us; speedup vs baseline: 1.0245x; 1.0245x over previous
//
#include <hip/hip_runtime.h>
#include <stdint.h>

// ---------------------------------------------------------------------------
// CommNetActor fused forward v14 — FP16 MFMA, 5 blocks/CU (gfx950).
//
//  R13 post-mortem: fat 512-thr blocks + hoist chain spilled (WRITE 5.9MB)
//  and regressed to 116us — hoisting doubles B-register storage and is
//  mutually exclusive with occupancy. v12 (89us, 4 blocks/CU) is the anchor.
//
//  v14 = v12 arithmetic BIT-IDENTICAL (absmax must stay 4.882812e-4), with
//  exactly two residency changes targeting 5 blocks/CU = 20 waves/CU:
//   1. LDS = exactly 32768B: Pbuf overlaid into X0 (X0 is dead after cl4's
//      reads). Pbuf zeroing moves after the cl4 barrier (+1 cheap barrier).
//      5 x 32768 = 163840B = the full 160KiB pool.
//   2. __launch_bounds__(256, 5): unified budget 102 >= measured ~96 demand
//      (64 arch + 32 acc), so no spill expected. Tripwire: WRITE_SIZE.
//
//  Structure (v12): 4096 blocks x 256 thr; 64 rows/block; distinct 32-col
//  wave ownership; full-layer B preload (zero VMEM in K-loops); ping-pong
//  X0<->X1 (1 barrier/layer); operand-swapped MFMA (lane = X-row, reg-quads
//  = col quads); fused comm via shfl_xor over adjacent agent lanes; atomic
//  dec reduce. MFMA C/D: col=lane&31, row=(r&3)+8*(r>>2)+4*(lane>>5).
// ---------------------------------------------------------------------------

typedef __attribute__((ext_vector_type(4)))  float f32x4;
typedef __attribute__((ext_vector_type(16))) float f32x16;
typedef __attribute__((ext_vector_type(8)))  _Float16 f16x8;
typedef __attribute__((ext_vector_type(4)))  _Float16 f16x4;

#define WS_HALF 106496   // total f16 elements in ws
#define SEG_ENC 0
#define SEG_FC1 8192
#define SEG_FC2 24576
#define SEG_FC3 40960
#define SEG_W1  57344
#define SEG_W2  73728
#define SEG_DEC 90112

#define MFMA16(a, b, c) __builtin_amdgcn_mfma_f32_32x32x16_f16((a), (b), (c), 0, 0, 0)

__device__ __forceinline__ unsigned short f16_bits(float f) {
  union { _Float16 h; unsigned short u; } cv;
  cv.h = (_Float16)f;   // RN-E
  return cv.u;
}
__device__ __forceinline__ f32x16 zero16() {
  f32x16 v;
#pragma unroll
  for (int i = 0; i < 16; ++i) v[i] = 0.0f;
  return v;
}
// swizzled f16 index: pitch 128, 16B groups XOR'd by row&15
__device__ __forceinline__ int xswz(int row, int g) {
  return row * 128 + ((g ^ (row & 15)) << 3);
}
// barrier draining LDS ops only — register-bound global loads stay in flight
__device__ __forceinline__ void barrier_lds() {
  asm volatile("s_waitcnt lgkmcnt(0)\n\ts_barrier" ::: "memory");
}

// ---------------------------------------------------------------------------
// Weight prep: f16 fragments. Frag f = kc*nbN + nb:
//   value = W[kc*16 + (lane>>5)*8 + j][nb*32 + (lane&31)]
// cl4 split into W1 = Wtop - 0.25*Wbot and W2 = 0.25*Wbot. dec padded N16->32.
// ---------------------------------------------------------------------------
__global__ void prep_weights(const float* __restrict__ enc_w, const float* __restrict__ fc1_w,
                             const float* __restrict__ fc2_w, const float* __restrict__ fc3_w,
                             const float* __restrict__ cl4_w, const float* __restrict__ dec_w,
                             unsigned short* __restrict__ ws) {
  int idx = blockIdx.x * 256 + threadIdx.x;
  if (idx >= WS_HALF) return;
  const float* W; int base, N, nbN, mode;
  if      (idx <  8192) { W = enc_w; base = SEG_ENC; N = 128; nbN = 4; mode = 0; }
  else if (idx < 24576) { W = fc1_w; base = SEG_FC1; N = 128; nbN = 4; mode = 0; }
  else if (idx < 40960) { W = fc2_w; base = SEG_FC2; N = 128; nbN = 4; mode = 0; }
  else if (idx < 57344) { W = fc3_w; base = SEG_FC3; N = 128; nbN = 4; mode = 0; }
  else if (idx < 73728) { W = cl4_w; base = SEG_W1;  N = 128; nbN = 4; mode = 1; }
  else if (idx < 90112) { W = cl4_w; base = SEG_W2;  N = 128; nbN = 4; mode = 2; }
  else                  { W = dec_w; base = SEG_DEC; N = 16;  nbN = 1; mode = 0; }
  int local = idx - base;
  int j    = local & 7;
  int lane = (local >> 3) & 63;
  int frag = local >> 9;
  int nb = frag % nbN;
  int kc = frag / nbN;
  int k = kc * 16 + ((lane >> 5) << 3) + j;
  int n = nb * 32 + (lane & 31);
  float wv;
  if (mode == 0)      wv = (n < N) ? W[k * N + n] : 0.0f;
  else if (mode == 1) wv = W[k * 128 + n] - 0.25f * W[(k + 128) * 128 + n];
  else                wv = 0.25f * W[(k + 128) * 128 + n];
  ws[idx] = f16_bits(wv);
}

// ---------------------------------------------------------------------------
// Standard layer: Xsrc[64][K] @ W[K][128] + b, act -> Xdst (ping-pong, no
// internal barrier). Operand-swapped. ALL KC B-chunks preloaded to registers
// before the K-loop: zero VMEM inside the loop.
// ---------------------------------------------------------------------------
template <int KC, int ACT>
__device__ __forceinline__ void layer_std(const short* __restrict__ Xsrc,
                                          short* __restrict__ Xdst,
                                          const unsigned short* __restrict__ wseg,
                                          const float* __restrict__ bias,
                                          int lr, int lh, int w) {
  const int l = lh * 32 + lr;
  const unsigned short* bp = wseg + w * 512 + l * 8;
  f16x8 Bh[KC];
#pragma unroll
  for (int kc = 0; kc < KC; ++kc) Bh[kc] = *(const f16x8*)(bp + kc * 2048);
  f32x4 bv[4];
#pragma unroll
  for (int q = 0; q < 4; ++q)
    bv[q] = *(const f32x4*)&bias[w * 32 + q * 8 + 4 * lh];
  f32x16 acc0 = zero16(), acc1 = zero16();
#pragma unroll
  for (int kc = 0; kc < KC; ++kc) {
    const int g = kc * 2 + lh;
    const int xi0 = xswz(lr, g), xi1 = xswz(lr + 32, g);
    const f16x8 ah0 = *(const f16x8*)&Xsrc[xi0];
    const f16x8 ah1 = *(const f16x8*)&Xsrc[xi1];
    acc0 = MFMA16(Bh[kc], ah0, acc0);
    acc1 = MFMA16(Bh[kc], ah1, acc1);
  }
#pragma unroll
  for (int mb = 0; mb < 2; ++mb) {
    const int row = mb * 32 + lr;
    const int rb = row & 15;
    const f32x16 a = mb ? acc1 : acc0;
#pragma unroll
    for (int q = 0; q < 4; ++q) {
      f16x4 hq;
#pragma unroll
      for (int t = 0; t < 4; ++t) {
        float v = a[q * 4 + t] + bv[q][t];
        if (ACT == 0)      v = __builtin_amdgcn_rcpf(1.0f + __expf(-v));  // sigmoid
        else if (ACT == 1) v = fmaxf(v, 0.0f);                            // relu
        hq[t] = (_Float16)v;
      }
      const int idx = row * 128 + (((w * 4 + q) ^ rb) << 3) + 4 * lh;
      *(f16x4*)&Xdst[idx] = hq;
    }
  }
}

// ---------------------------------------------------------------------------
// cl4 band MB (rows MB*32..+31, cols w*32..+31): a1=(H3@W1)^T, a2=(H3@W2)^T,
// ring-4 B prefetch per matrix (8 chunks in flight). Agents = adjacent lanes
// -> T = shfl_xor(1)+shfl_xor(2). Writes H4 to Xdst (ping-pong, no barrier).
// ---------------------------------------------------------------------------
template <int MB>
__device__ __forceinline__ void cl4_band(const short* __restrict__ Xsrc,
                                         short* __restrict__ Xdst,
                                         const unsigned short* __restrict__ ws,
                                         const float* __restrict__ cl4_b,
                                         int lr, int lh, int w) {
  const int l = lh * 32 + lr;
  const unsigned short* b1p = ws + SEG_W1 + w * 512 + l * 8;
  const unsigned short* b2p = ws + SEG_W2 + w * 512 + l * 8;
  f16x8 B1[4], B2[4];
#pragma unroll
  for (int k = 0; k < 4; ++k) {
    B1[k] = *(const f16x8*)(b1p + k * 2048);
    B2[k] = *(const f16x8*)(b2p + k * 2048);
  }
  f32x4 bv[4];
#pragma unroll
  for (int q = 0; q < 4; ++q)
    bv[q] = *(const f32x4*)&cl4_b[w * 32 + q * 8 + 4 * lh];
  f32x16 a1 = zero16(), a2 = zero16();
#pragma unroll
  for (int kc = 0; kc < 8; ++kc) {
    const int cur = kc & 3;
    const int xi = xswz(MB * 32 + lr, kc * 2 + lh);
    const f16x8 ah = *(const f16x8*)&Xsrc[xi];
    a1 = MFMA16(B1[cur], ah, a1);
    a2 = MFMA16(B2[cur], ah, a2);
    if (kc + 4 < 8) {
      B1[cur] = *(const f16x8*)(b1p + (kc + 4) * 2048);
      B2[cur] = *(const f16x8*)(b2p + (kc + 4) * 2048);
    }
  }
  const int row = MB * 32 + lr;
  const int rb = row & 15;
#pragma unroll
  for (int q = 0; q < 4; ++q) {
    f16x4 hq;
#pragma unroll
    for (int t = 0; t < 4; ++t) {
      const int r = q * 4 + t;
      float t2 = a2[r];
      t2 += __shfl_xor(t2, 1);   // agents are adjacent lanes 4b..4b+3
      t2 += __shfl_xor(t2, 2);
      hq[t] = (_Float16)(a1[r] + t2 + bv[q][t]);
    }
    const int idx = row * 128 + (((w * 4 + q) ^ rb) << 3) + 4 * lh;
    *(f16x4*)&Xdst[idx] = hq;
  }
}

// ---------------------------------------------------------------------------
__global__ __launch_bounds__(256, 5)
void commnet_fwd(const float* __restrict__ O,
                 const float* __restrict__ enc_b, const float* __restrict__ fc1_b,
                 const float* __restrict__ fc2_b, const float* __restrict__ fc3_b,
                 const float* __restrict__ cl4_b, const float* __restrict__ dec_b,
                 const unsigned short* __restrict__ ws, float* __restrict__ out) {
  __shared__ __attribute__((aligned(16))) short X0[64 * 128];   // 16 KB
  __shared__ __attribute__((aligned(16))) short X1[64 * 128];   // 16 KB
  // total LDS = exactly 32768 B -> 5 blocks/CU. Pbuf overlays X0 (dead after
  // cl4's reads): 272 floats = 1088 B inside the 16 KB.
  float* Pbuf = (float*)X0;

  const int tid = threadIdx.x;
  const int l = tid & 63, w = tid >> 6;
  const int lr = l & 31, lh = l >> 5;

  // ---- stage O [64 x 64] f32 -> f16 -> swizzled X0 groups 0..7 ----
  {
    const f32x4* Og = (const f32x4*)(O + (long)blockIdx.x * 4096);
#pragma unroll
    for (int it = 0; it < 4; ++it) {
      const int i = it * 256 + tid;       // 0..1023
      const int row = i >> 4;
      const int c4 = (i & 15) << 2;
      f32x4 v = Og[i];
      f16x4 hv;
#pragma unroll
      for (int j = 0; j < 4; ++j) hv[j] = (_Float16)v[j];
      const int bi = row * 128 + (((c4 >> 3) ^ (row & 15)) << 3) + (c4 & 7);
      *(f16x4*)&X0[bi] = hv;
    }
  }
  barrier_lds();   // X0 staged

  layer_std<4, 0>(X0, X1, ws + SEG_ENC, enc_b, lr, lh, w);
  barrier_lds();   // H0 in X1
  layer_std<8, 1>(X1, X0, ws + SEG_FC1, fc1_b, lr, lh, w);
  barrier_lds();   // H1 in X0
  layer_std<8, 1>(X0, X1, ws + SEG_FC2, fc2_b, lr, lh, w);
  barrier_lds();   // H2 in X1
  layer_std<8, 1>(X1, X0, ws + SEG_FC3, fc3_b, lr, lh, w);
  barrier_lds();   // H3 in X0

  // ---- cl4: both bands read X0, write X1; no barrier between bands ----
  cl4_band<0>(X0, X1, ws, cl4_b, lr, lh, w);
  cl4_band<1>(X0, X1, ws, cl4_b, lr, lh, w);
  barrier_lds();   // H4 in X1 visible; all X0 reads done -> X0 reusable as Pbuf

  // zero ALL 272 partial slots (R9 lesson: X0 holds stale activations here)
  Pbuf[tid] = 0.0f;
  if (tid < 16) Pbuf[256 + tid] = 0.0f;
  barrier_lds();   // zeros visible

  // ---- dec: [16 x 512] @ dec_w(pad32); 8 kc/wave, ALL preloaded; atomics ----
  {
    const unsigned short* bp = ws + SEG_DEC + (w * 8) * 512 + l * 8;
    f16x8 Bh[8];
#pragma unroll
    for (int kq = 0; kq < 8; ++kq) Bh[kq] = *(const f16x8*)(bp + kq * 512);
    f32x16 dacc = zero16();
#pragma unroll
    for (int kq = 0; kq < 8; ++kq) {
      const int kcg = w * 8 + kq;          // global k-chunk 0..31
      const int k0 = kcg * 16 + lh * 8;    // 0..504
      const int agent = k0 >> 7;
      const int d0 = k0 & 127;
      const int row = (lr & 15) * 4 + agent;   // batch (dup for lr>=16), agent
      const int xi = xswz(row, d0 >> 3);
      const f16x8 ah = *(const f16x8*)&X1[xi];
      dacc = MFMA16(Bh[kq], ah, dacc);     // swapped: weights in A-slot
    }
    if (lr < 16) {   // lane = batch; reg r -> action (r&3)+8*(r>>2)+4*lh
#pragma unroll
      for (int r = 0; r < 8; ++r) {
        const int action = (r & 3) + 8 * (r >> 2) + 4 * lh;   // 0..15
        atomicAdd(&Pbuf[lr * 17 + action], dacc[r]);
      }
    }
  }
  barrier_lds();   // partials complete

  // ---- + bias, softmax over 16 actions, coalesced store ----
  {
    const int c = tid & 15;
    float v = Pbuf[(tid >> 4) * 17 + c] + dec_b[c];
    float m = v;
#pragma unroll
    for (int mk = 1; mk < 16; mk <<= 1) m = fmaxf(m, __shfl_xor(m, mk, 16));
    const float e = __expf(v - m);
    float s = e;
#pragma unroll
    for (int mk = 1; mk < 16; mk <<= 1) s += __shfl_xor(s, mk, 16);
    out[(long)blockIdx.x * 256 + tid] = e * __builtin_amdgcn_rcpf(s);
  }
}

// ---------------------------------------------------------------------------
extern "C" void kernel_launch(void* const* d_in, const int* in_sizes, int n_in,
                              void* d_out, int out_size, void* d_ws, size_t ws_size,
                              hipStream_t stream) {
  (void)n_in; (void)out_size; (void)ws_size;  // needs ws_size >= 212,992 B
  const float* O     = (const float*)d_in[0];
  const float* enc_w = (const float*)d_in[1];
  const float* enc_b = (const float*)d_in[2];
  const float* fc1_w = (const float*)d_in[3];
  const float* fc1_b = (const float*)d_in[4];
  const float* fc2_w = (const float*)d_in[5];
  const float* fc2_b = (const float*)d_in[6];
  const float* fc3_w = (const float*)d_in[7];
  const float* fc3_b = (const float*)d_in[8];
  const float* cl4_w = (const float*)d_in[9];
  const float* cl4_b = (const float*)d_in[10];
  const float* dec_w = (const float*)d_in[11];
  const float* dec_b = (const float*)d_in[12];
  unsigned short* wsb = (unsigned short*)d_ws;

  prep_weights<<<(WS_HALF + 255) / 256, 256, 0, stream>>>(enc_w, fc1_w, fc2_w, fc3_w,
                                                          cl4_w, dec_w, wsb);
  const int rows   = in_sizes[0] / 64;   // B*A = 262144
  const int blocks = rows / 64;          // 4096
  commnet_fwd<<<blocks, 256, 0, stream>>>(O, enc_b, fc1_b, fc2_b, fc3_b, cl4_b,
                                          dec_b, wsb, (float*)d_out);
}

// Round 15
// 90.558 us; speedup vs baseline: 1.3016x; 1.2704x over previous
//
#include <hip/hip_runtime.h>
#include <stdint.h>

// ---------------------------------------------------------------------------
// CommNetActor fused forward v15 — FP16 MFMA, ring-3 A-prefetch (gfx950).
//
//  R14 post-mortem: 5 blocks/CU infeasible — (256,5)=102 unified forced 48
//  arch VGPR -> 123MB spill. Resident blocks are register-capped at 4/CU.
//  v12 (94us rocprof) is the anchor; TLP is maxed (3.2 waves/SIMD avg).
//
//  v15 = v12 with ILP instead: per-wave stall accounting (4K issue cycles,
//  ~10K stall per wave) matches ~80 ds_read_b128 x ~100cyc exposed latency.
//  Fix: explicit ring-3 A-fragment prefetch in EVERY K-loop (std layers,
//  cl4 bands, dec): issue iteration kc+2's reads before consuming kc's.
//  Reads for kc+2 fly under the MFMAs of kc,kc+1. +16-24 VGPR (~110 total
//  < 128 budget). Arithmetic BIT-IDENTICAL (absmax must stay 4.882812e-4).
//
//  Structure (v12): 4096 blocks x 256 thr; 64 rows/block; distinct 32-col
//  wave ownership; full-layer B preload (zero VMEM in K-loops); ping-pong
//  X0<->X1 (1 barrier/layer); operand-swapped MFMA (lane = X-row, reg-quads
//  = col quads); fused comm via shfl_xor; atomic dec reduce; LDS 34.3KB ->
//  4 blocks/CU. MFMA C/D: col=lane&31, row=(r&3)+8*(r>>2)+4*(lane>>5).
// ---------------------------------------------------------------------------

typedef __attribute__((ext_vector_type(4)))  float f32x4;
typedef __attribute__((ext_vector_type(16))) float f32x16;
typedef __attribute__((ext_vector_type(8)))  _Float16 f16x8;
typedef __attribute__((ext_vector_type(4)))  _Float16 f16x4;

#define WS_HALF 106496   // total f16 elements in ws
#define SEG_ENC 0
#define SEG_FC1 8192
#define SEG_FC2 24576
#define SEG_FC3 40960
#define SEG_W1  57344
#define SEG_W2  73728
#define SEG_DEC 90112

#define MFMA16(a, b, c) __builtin_amdgcn_mfma_f32_32x32x16_f16((a), (b), (c), 0, 0, 0)

__device__ __forceinline__ unsigned short f16_bits(float f) {
  union { _Float16 h; unsigned short u; } cv;
  cv.h = (_Float16)f;   // RN-E
  return cv.u;
}
__device__ __forceinline__ f32x16 zero16() {
  f32x16 v;
#pragma unroll
  for (int i = 0; i < 16; ++i) v[i] = 0.0f;
  return v;
}
// swizzled f16 index: pitch 128, 16B groups XOR'd by row&15
__device__ __forceinline__ int xswz(int row, int g) {
  return row * 128 + ((g ^ (row & 15)) << 3);
}
// barrier draining LDS ops only — register-bound global loads stay in flight
__device__ __forceinline__ void barrier_lds() {
  asm volatile("s_waitcnt lgkmcnt(0)\n\ts_barrier" ::: "memory");
}

// ---------------------------------------------------------------------------
// Weight prep: f16 fragments. Frag f = kc*nbN + nb:
//   value = W[kc*16 + (lane>>5)*8 + j][nb*32 + (lane&31)]
// cl4 split into W1 = Wtop - 0.25*Wbot and W2 = 0.25*Wbot. dec padded N16->32.
// ---------------------------------------------------------------------------
__global__ void prep_weights(const float* __restrict__ enc_w, const float* __restrict__ fc1_w,
                             const float* __restrict__ fc2_w, const float* __restrict__ fc3_w,
                             const float* __restrict__ cl4_w, const float* __restrict__ dec_w,
                             unsigned short* __restrict__ ws) {
  int idx = blockIdx.x * 256 + threadIdx.x;
  if (idx >= WS_HALF) return;
  const float* W; int base, N, nbN, mode;
  if      (idx <  8192) { W = enc_w; base = SEG_ENC; N = 128; nbN = 4; mode = 0; }
  else if (idx < 24576) { W = fc1_w; base = SEG_FC1; N = 128; nbN = 4; mode = 0; }
  else if (idx < 40960) { W = fc2_w; base = SEG_FC2; N = 128; nbN = 4; mode = 0; }
  else if (idx < 57344) { W = fc3_w; base = SEG_FC3; N = 128; nbN = 4; mode = 0; }
  else if (idx < 73728) { W = cl4_w; base = SEG_W1;  N = 128; nbN = 4; mode = 1; }
  else if (idx < 90112) { W = cl4_w; base = SEG_W2;  N = 128; nbN = 4; mode = 2; }
  else                  { W = dec_w; base = SEG_DEC; N = 16;  nbN = 1; mode = 0; }
  int local = idx - base;
  int j    = local & 7;
  int lane = (local >> 3) & 63;
  int frag = local >> 9;
  int nb = frag % nbN;
  int kc = frag / nbN;
  int k = kc * 16 + ((lane >> 5) << 3) + j;
  int n = nb * 32 + (lane & 31);
  float wv;
  if (mode == 0)      wv = (n < N) ? W[k * N + n] : 0.0f;
  else if (mode == 1) wv = W[k * 128 + n] - 0.25f * W[(k + 128) * 128 + n];
  else                wv = 0.25f * W[(k + 128) * 128 + n];
  ws[idx] = f16_bits(wv);
}

// ---------------------------------------------------------------------------
// Standard layer: Xsrc[64][K] @ W[K][128] + b, act -> Xdst (ping-pong).
// Operand-swapped; all KC B-chunks preloaded; A-fragments ring-3 prefetched
// (kc+2's ds_reads issue before kc's MFMAs consume).
// ---------------------------------------------------------------------------
template <int KC, int ACT>
__device__ __forceinline__ void layer_std(const short* __restrict__ Xsrc,
                                          short* __restrict__ Xdst,
                                          const unsigned short* __restrict__ wseg,
                                          const float* __restrict__ bias,
                                          int lr, int lh, int w) {
  const int l = lh * 32 + lr;
  const unsigned short* bp = wseg + w * 512 + l * 8;
  f16x8 Bh[KC];
#pragma unroll
  for (int kc = 0; kc < KC; ++kc) Bh[kc] = *(const f16x8*)(bp + kc * 2048);
  f32x4 bv[4];
#pragma unroll
  for (int q = 0; q < 4; ++q)
    bv[q] = *(const f32x4*)&bias[w * 32 + q * 8 + 4 * lh];
  // ring-3 A prefetch
  f16x8 A0[3], A1[3];
#pragma unroll
  for (int p = 0; p < 2 && p < KC; ++p) {
    const int g = p * 2 + lh;
    A0[p] = *(const f16x8*)&Xsrc[xswz(lr, g)];
    A1[p] = *(const f16x8*)&Xsrc[xswz(lr + 32, g)];
  }
  f32x16 acc0 = zero16(), acc1 = zero16();
#pragma unroll
  for (int kc = 0; kc < KC; ++kc) {
    const int cur = kc % 3;
    if (kc + 2 < KC) {
      const int nx = (kc + 2) % 3;
      const int g = (kc + 2) * 2 + lh;
      A0[nx] = *(const f16x8*)&Xsrc[xswz(lr, g)];
      A1[nx] = *(const f16x8*)&Xsrc[xswz(lr + 32, g)];
    }
    acc0 = MFMA16(Bh[kc], A0[cur], acc0);
    acc1 = MFMA16(Bh[kc], A1[cur], acc1);
  }
#pragma unroll
  for (int mb = 0; mb < 2; ++mb) {
    const int row = mb * 32 + lr;
    const int rb = row & 15;
    const f32x16 a = mb ? acc1 : acc0;
#pragma unroll
    for (int q = 0; q < 4; ++q) {
      f16x4 hq;
#pragma unroll
      for (int t = 0; t < 4; ++t) {
        float v = a[q * 4 + t] + bv[q][t];
        if (ACT == 0)      v = __builtin_amdgcn_rcpf(1.0f + __expf(-v));  // sigmoid
        else if (ACT == 1) v = fmaxf(v, 0.0f);                            // relu
        hq[t] = (_Float16)v;
      }
      const int idx = row * 128 + (((w * 4 + q) ^ rb) << 3) + 4 * lh;
      *(f16x4*)&Xdst[idx] = hq;
    }
  }
}

// ---------------------------------------------------------------------------
// cl4 band MB (rows MB*32..+31, cols w*32..+31): a1=(H3@W1)^T, a2=(H3@W2)^T,
// B ring-4 per matrix + A ring-3. Agents = adjacent lanes -> T via
// shfl_xor(1)+shfl_xor(2). Writes H4 to Xdst (ping-pong, no barrier).
// ---------------------------------------------------------------------------
template <int MB>
__device__ __forceinline__ void cl4_band(const short* __restrict__ Xsrc,
                                         short* __restrict__ Xdst,
                                         const unsigned short* __restrict__ ws,
                                         const float* __restrict__ cl4_b,
                                         int lr, int lh, int w) {
  const int l = lh * 32 + lr;
  const unsigned short* b1p = ws + SEG_W1 + w * 512 + l * 8;
  const unsigned short* b2p = ws + SEG_W2 + w * 512 + l * 8;
  f16x8 B1[4], B2[4];
#pragma unroll
  for (int k = 0; k < 4; ++k) {
    B1[k] = *(const f16x8*)(b1p + k * 2048);
    B2[k] = *(const f16x8*)(b2p + k * 2048);
  }
  f32x4 bv[4];
#pragma unroll
  for (int q = 0; q < 4; ++q)
    bv[q] = *(const f32x4*)&cl4_b[w * 32 + q * 8 + 4 * lh];
  // ring-3 A prefetch
  f16x8 Ax[3];
#pragma unroll
  for (int p = 0; p < 2; ++p)
    Ax[p] = *(const f16x8*)&Xsrc[xswz(MB * 32 + lr, p * 2 + lh)];
  f32x16 a1 = zero16(), a2 = zero16();
#pragma unroll
  for (int kc = 0; kc < 8; ++kc) {
    const int cur3 = kc % 3;
    if (kc + 2 < 8) {
      Ax[(kc + 2) % 3] = *(const f16x8*)&Xsrc[xswz(MB * 32 + lr, (kc + 2) * 2 + lh)];
    }
    a1 = MFMA16(B1[kc & 3], Ax[cur3], a1);
    a2 = MFMA16(B2[kc & 3], Ax[cur3], a2);
    if (kc + 4 < 8) {
      B1[kc & 3] = *(const f16x8*)(b1p + (kc + 4) * 2048);
      B2[kc & 3] = *(const f16x8*)(b2p + (kc + 4) * 2048);
    }
  }
  const int row = MB * 32 + lr;
  const int rb = row & 15;
#pragma unroll
  for (int q = 0; q < 4; ++q) {
    f16x4 hq;
#pragma unroll
    for (int t = 0; t < 4; ++t) {
      const int r = q * 4 + t;
      float t2 = a2[r];
      t2 += __shfl_xor(t2, 1);   // agents are adjacent lanes 4b..4b+3
      t2 += __shfl_xor(t2, 2);
      hq[t] = (_Float16)(a1[r] + t2 + bv[q][t]);
    }
    const int idx = row * 128 + (((w * 4 + q) ^ rb) << 3) + 4 * lh;
    *(f16x4*)&Xdst[idx] = hq;
  }
}

// ---------------------------------------------------------------------------
__global__ __launch_bounds__(256, 4)
void commnet_fwd(const float* __restrict__ O,
                 const float* __restrict__ enc_b, const float* __restrict__ fc1_b,
                 const float* __restrict__ fc2_b, const float* __restrict__ fc3_b,
                 const float* __restrict__ cl4_b, const float* __restrict__ dec_b,
                 const unsigned short* __restrict__ ws, float* __restrict__ out) {
  __shared__ __attribute__((aligned(16))) short X0[64 * 128];   // 16 KB
  __shared__ __attribute__((aligned(16))) short X1[64 * 128];   // 16 KB
  __shared__ __attribute__((aligned(16))) float Pbuf[272];      // 1.06 KB (16x17)

  const int tid = threadIdx.x;
  const int l = tid & 63, w = tid >> 6;
  const int lr = l & 31, lh = l >> 5;

  // zero ALL 272 partial slots (R9 lesson)
  Pbuf[tid] = 0.0f;
  if (tid < 16) Pbuf[256 + tid] = 0.0f;

  // ---- stage O [64 x 64] f32 -> f16 -> swizzled X0 groups 0..7 ----
  {
    const f32x4* Og = (const f32x4*)(O + (long)blockIdx.x * 4096);
#pragma unroll
    for (int it = 0; it < 4; ++it) {
      const int i = it * 256 + tid;       // 0..1023
      const int row = i >> 4;
      const int c4 = (i & 15) << 2;
      f32x4 v = Og[i];
      f16x4 hv;
#pragma unroll
      for (int j = 0; j < 4; ++j) hv[j] = (_Float16)v[j];
      const int bi = row * 128 + (((c4 >> 3) ^ (row & 15)) << 3) + (c4 & 7);
      *(f16x4*)&X0[bi] = hv;
    }
  }
  barrier_lds();   // X0 staged

  layer_std<4, 0>(X0, X1, ws + SEG_ENC, enc_b, lr, lh, w);
  barrier_lds();   // H0 in X1
  layer_std<8, 1>(X1, X0, ws + SEG_FC1, fc1_b, lr, lh, w);
  barrier_lds();   // H1 in X0
  layer_std<8, 1>(X0, X1, ws + SEG_FC2, fc2_b, lr, lh, w);
  barrier_lds();   // H2 in X1
  layer_std<8, 1>(X1, X0, ws + SEG_FC3, fc3_b, lr, lh, w);
  barrier_lds();   // H3 in X0

  // ---- cl4: both bands read X0, write X1; no barrier between bands ----
  cl4_band<0>(X0, X1, ws, cl4_b, lr, lh, w);
  cl4_band<1>(X0, X1, ws, cl4_b, lr, lh, w);
  barrier_lds();   // H4 in X1

  // ---- dec: [16 x 512] @ dec_w(pad32); 8 kc/wave, B preloaded, A ring-3 ----
  {
    const unsigned short* bp = ws + SEG_DEC + (w * 8) * 512 + l * 8;
    f16x8 Bh[8];
#pragma unroll
    for (int kq = 0; kq < 8; ++kq) Bh[kq] = *(const f16x8*)(bp + kq * 512);
    // A addresses: row = (lr&15)*4 + agent, depends on kq
    f16x8 Ax[3];
#pragma unroll
    for (int p = 0; p < 2; ++p) {
      const int kcg = w * 8 + p;
      const int k0 = kcg * 16 + lh * 8;
      const int row = (lr & 15) * 4 + (k0 >> 7);
      Ax[p] = *(const f16x8*)&X1[xswz(row, (k0 & 127) >> 3)];
    }
    f32x16 dacc = zero16();
#pragma unroll
    for (int kq = 0; kq < 8; ++kq) {
      const int cur = kq % 3;
      if (kq + 2 < 8) {
        const int kcg = w * 8 + kq + 2;
        const int k0 = kcg * 16 + lh * 8;
        const int row = (lr & 15) * 4 + (k0 >> 7);
        Ax[(kq + 2) % 3] = *(const f16x8*)&X1[xswz(row, (k0 & 127) >> 3)];
      }
      dacc = MFMA16(Bh[kq], Ax[cur], dacc);   // swapped: weights in A-slot
    }
    if (lr < 16) {   // lane = batch; reg r -> action (r&3)+8*(r>>2)+4*lh
#pragma unroll
      for (int r = 0; r < 8; ++r) {
        const int action = (r & 3) + 8 * (r >> 2) + 4 * lh;   // 0..15
        atomicAdd(&Pbuf[lr * 17 + action], dacc[r]);
      }
    }
  }
  barrier_lds();   // partials complete

  // ---- + bias, softmax over 16 actions, coalesced store ----
  {
    const int c = tid & 15;
    float v = Pbuf[(tid >> 4) * 17 + c] + dec_b[c];
    float m = v;
#pragma unroll
    for (int mk = 1; mk < 16; mk <<= 1) m = fmaxf(m, __shfl_xor(m, mk, 16));
    const float e = __expf(v - m);
    float s = e;
#pragma unroll
    for (int mk = 1; mk < 16; mk <<= 1) s += __shfl_xor(s, mk, 16);
    out[(long)blockIdx.x * 256 + tid] = e * __builtin_amdgcn_rcpf(s);
  }
}

// ---------------------------------------------------------------------------
extern "C" void kernel_launch(void* const* d_in, const int* in_sizes, int n_in,
                              void* d_out, int out_size, void* d_ws, size_t ws_size,
                              hipStream_t stream) {
  (void)n_in; (void)out_size; (void)ws_size;  // needs ws_size >= 212,992 B
  const float* O     = (const float*)d_in[0];
  const float* enc_w = (const float*)d_in[1];
  const float* enc_b = (const float*)d_in[2];
  const float* fc1_w = (const float*)d_in[3];
  const float* fc1_b = (const float*)d_in[4];
  const float* fc2_w = (const float*)d_in[5];
  const float* fc2_b = (const float*)d_in[6];
  const float* fc3_w = (const float*)d_in[7];
  const float* fc3_b = (const float*)d_in[8];
  const float* cl4_w = (const float*)d_in[9];
  const float* cl4_b = (const float*)d_in[10];
  const float* dec_w = (const float*)d_in[11];
  const float* dec_b = (const float*)d_in[12];
  unsigned short* wsb = (unsigned short*)d_ws;

  prep_weights<<<(WS_HALF + 255) / 256, 256, 0, stream>>>(enc_w, fc1_w, fc2_w, fc3_w,
                                                          cl4_w, dec_w, wsb);
  const int rows   = in_sizes[0] / 64;   // B*A = 262144
  const int blocks = rows / 64;          // 4096
  commnet_fwd<<<blocks, 256, 0, stream>>>(O, enc_b, fc1_b, fc2_b, fc3_b, cl4_b,
                                          dec_b, wsb, (float*)d_out);
}